// Round 11
// baseline (83.313 us; speedup 1.0000x reference)
//
#include <hip/hip_runtime.h>
#include <hip/hip_bf16.h>

// GraphSage: h1 = segsum(val * x[dst] -> src) / deg; out = [x, h1norm] @ W
// N=50000, D=128, E=800000, W [256,128] fp32, out [N,128] fp32.
//
// Round-11 structure:
//   k1 bincount : per-tile LDS histogram -> counts[tile][part]
//   k2 fused    : per-partition scan (exact tile write bases) + x f32->bf16
//                 + W MFMA-fragment pack
//   k3 place    : LDS cursors -> partition queues (only LDS atomics)
//   k4 gather_gemm : per-partition (32 nodes) LDS CSR + 8-wave gather with
//                 4-node-interleaved loads (16 in flight) -> swizzled LDS h1
//                 tile + fused 32-row MFMA GEMM -> out

#define N_NODES 50000
#define DIM 128
#define N_EDGES 800000
#define NPART 1568      // partitions of PN=32 nodes (1568*32 = 50176)
#define PN 32
#define QCAP 768        // per-partition cap (mean 510, ~+11 sigma)
#define BIN_T 4096
#define T_TILES 196     // ceil(800000/4096)
#define XB 6250         // convert blocks (N*DIM/4/256)
#define WCONV_B 16

typedef __attribute__((ext_vector_type(8))) short bf16x8;
typedef __attribute__((ext_vector_type(4))) float f32x4;

__device__ __forceinline__ unsigned short f2bf(float f) {
    unsigned int u = __float_as_uint(f);
    unsigned int r = (u + 0x7FFFu + ((u >> 16) & 1u)) >> 16;
    return (unsigned short)r;
}
__device__ __forceinline__ float bf_lo(unsigned int u) {
    return __uint_as_float(u << 16);
}
__device__ __forceinline__ float bf_hi(unsigned int u) {
    return __uint_as_float(u & 0xFFFF0000u);
}

// 4-edge gather step (4 independent loads; split accumulator chains)
__device__ __forceinline__ void gath4(const int2* csr, const unsigned int* xu,
    int lane, int j, float& ax0, float& ax1, float& ay0, float& ay1,
    float& dg0, float& dg1)
{
    int2 e0 = csr[j + 0]; int2 e1 = csr[j + 1];
    int2 e2 = csr[j + 2]; int2 e3 = csr[j + 3];
    unsigned int u0 = xu[(size_t)e0.x * 64 + lane];
    unsigned int u1 = xu[(size_t)e1.x * 64 + lane];
    unsigned int u2 = xu[(size_t)e2.x * 64 + lane];
    unsigned int u3 = xu[(size_t)e3.x * 64 + lane];
    float v0 = __int_as_float(e0.y); float v1 = __int_as_float(e1.y);
    float v2 = __int_as_float(e2.y); float v3 = __int_as_float(e3.y);
    ax0 += v0 * bf_lo(u0) + v1 * bf_lo(u1);
    ax1 += v2 * bf_lo(u2) + v3 * bf_lo(u3);
    ay0 += v0 * bf_hi(u0) + v1 * bf_hi(u1);
    ay1 += v2 * bf_hi(u2) + v3 * bf_hi(u3);
    dg0 += v0 + v1;
    dg1 += v2 + v3;
}

__device__ __forceinline__ void gath1(const int2* csr, const unsigned int* xu,
    int lane, int j, float& ax0, float& ay0, float& dg0)
{
    int2 e0 = csr[j];
    unsigned int u0 = xu[(size_t)e0.x * 64 + lane];
    float v0 = __int_as_float(e0.y);
    ax0 += v0 * bf_lo(u0);
    ay0 += v0 * bf_hi(u0);
    dg0 += v0;
}

__device__ __forceinline__ void h1store(unsigned int* h1s, int ls, int lane,
                                        float ax, float ay, float dg)
{
    float inv = 1.0f / (dg + 1e-6f);
    unsigned int o = ((unsigned int)f2bf(ay * inv) << 16) | f2bf(ax * inv);
    h1s[ls * 64 + (lane ^ ((ls & 7) << 2))] = o;   // bank-swizzled
}

// ---------------------------------------------------------------------------
// k1: per-tile partition histogram. 196 blocks x 512 threads.
// ---------------------------------------------------------------------------
__global__ __launch_bounds__(512) void bincount_kernel(
    const int* __restrict__ esrc, int* __restrict__ counts)
{
    __shared__ int hist[NPART];
    int t = threadIdx.x;
    int b = blockIdx.x;

    for (int i = t; i < NPART; i += 512) hist[i] = 0;
    __syncthreads();

    int e0 = b * BIN_T;
    #pragma unroll
    for (int i = t; i < BIN_T; i += 512) {
        int e = e0 + i;
        if (e < N_EDGES) {
            int P = esrc[e] >> 5;          // PN = 32
            atomicAdd(&hist[P], 1);
        }
    }
    __syncthreads();
    for (int i = t; i < NPART; i += 512)
        counts[b * NPART + i] = hist[i];
}

// ---------------------------------------------------------------------------
// k2 fused: blocks [0,NPART): per-partition exclusive scan across tiles
//           blocks [NPART,NPART+XB): x f32->bf16
//           blocks [NPART+XB,...): W pack into MFMA B-fragment order
// ---------------------------------------------------------------------------
__global__ __launch_bounds__(256) void scan_xconv_wconv_kernel(
    int* __restrict__ counts, int* __restrict__ qcount,
    const float* __restrict__ x, unsigned short* __restrict__ xh,
    const float* __restrict__ W, unsigned short* __restrict__ wfrag)
{
    int b = blockIdx.x;
    int t = threadIdx.x;

    if (b < NPART) {
        __shared__ int s[256];
        int v = (t < T_TILES) ? counts[t * NPART + b] : 0;
        s[t] = v;
        __syncthreads();
        #pragma unroll
        for (int d = 1; d < 256; d <<= 1) {
            int tmp = (t >= d) ? s[t - d] : 0;
            __syncthreads();
            s[t] += tmp;
            __syncthreads();
        }
        if (t < T_TILES) counts[t * NPART + b] = s[t] - v;
        if (t == T_TILES - 1) qcount[b] = s[t];
        return;
    }

    if (b < NPART + XB) {
        int i = (b - NPART) * 256 + t;            // < 1,600,000 float4s
        float4 v = reinterpret_cast<const float4*>(x)[i];
        ushort4 o;
        o.x = f2bf(v.x); o.y = f2bf(v.y); o.z = f2bf(v.z); o.w = f2bf(v.w);
        reinterpret_cast<ushort4*>(xh)[i] = o;
        return;
    }

    {
        // Wfrag[((nt*8+ks)*64+l)*8+j] = bf16(W[ks*32+(l>>4)*8+j][nt*16+(l&15)])
        int idx = (b - NPART - XB) * 256 + t;     // 0..4095
        int l  = idx & 63;
        int ks = (idx >> 6) & 7;
        int nt = idx >> 9;
        int col  = nt * 16 + (l & 15);
        int krow = ks * 32 + (l >> 4) * 8;
        ushort4 lo, hi;
        lo.x = f2bf(W[(krow + 0) * DIM + col]);
        lo.y = f2bf(W[(krow + 1) * DIM + col]);
        lo.z = f2bf(W[(krow + 2) * DIM + col]);
        lo.w = f2bf(W[(krow + 3) * DIM + col]);
        hi.x = f2bf(W[(krow + 4) * DIM + col]);
        hi.y = f2bf(W[(krow + 5) * DIM + col]);
        hi.z = f2bf(W[(krow + 6) * DIM + col]);
        hi.w = f2bf(W[(krow + 7) * DIM + col]);
        reinterpret_cast<ushort4*>(wfrag)[idx * 2 + 0] = lo;
        reinterpret_cast<ushort4*>(wfrag)[idx * 2 + 1] = hi;
    }
}

// ---------------------------------------------------------------------------
// k3: place edges into partition queues using exact scanned bases.
// ---------------------------------------------------------------------------
__global__ __launch_bounds__(512) void place_kernel(
    const int* __restrict__ esrc, const int* __restrict__ edst,
    const float* __restrict__ eval, const int* __restrict__ counts,
    int2* __restrict__ queue)
{
    __shared__ int cur[NPART];
    int t = threadIdx.x;
    int b = blockIdx.x;

    for (int i = t; i < NPART; i += 512)
        cur[i] = counts[b * NPART + i];
    __syncthreads();

    int e0 = b * BIN_T;
    #pragma unroll
    for (int i = t; i < BIN_T; i += 512) {
        int e = e0 + i;
        if (e < N_EDGES) {
            int s = esrc[e];
            int P = s >> 5;
            int ls = s & 31;
            int pos = atomicAdd(&cur[P], 1);
            if (pos < QCAP) {
                int2 pk;
                pk.x = ls | (edst[e] << 5);       // < 2^21, positive
                pk.y = __float_as_int(eval[e]);
                queue[(size_t)P * QCAP + pos] = pk;
            }
        }
    }
}

// ---------------------------------------------------------------------------
// k4: fused gather + GEMM. One 512-thread block per partition (32 nodes).
// Phase A: build per-partition CSR in LDS.
// Phase B: each wave interleaves its 4 nodes (16 loads in flight).
// Phase C: 32-row MFMA GEMM: out = [xh | h1] @ W.
// ---------------------------------------------------------------------------
__global__ __launch_bounds__(512) void gather_gemm_kernel(
    const unsigned short* __restrict__ xh,
    const int2* __restrict__ queue, const int* __restrict__ qcount,
    const unsigned short* __restrict__ wfrag,
    float* __restrict__ out)
{
    __shared__ int cnt[PN];
    __shared__ int off[PN];
    __shared__ int cur[PN];
    __shared__ int2 csr[QCAP];
    __shared__ unsigned int h1s[PN * 64];   // row-major uint (2 bf16), swizzled

    int b = blockIdx.x;
    int t = threadIdx.x;

    int n = qcount[b];
    if (n > QCAP) n = QCAP;
    const int2* q = queue + (size_t)b * QCAP;

    // ---- Phase A: LDS CSR ----
    if (t < PN) cnt[t] = 0;
    __syncthreads();
    for (int i = t; i < n; i += 512)
        atomicAdd(&cnt[q[i].x & 31], 1);
    __syncthreads();
    if (t < PN) off[t] = cnt[t];
    __syncthreads();
    #pragma unroll
    for (int d = 1; d < PN; d <<= 1) {
        int v = 0;
        if (t < PN && t >= d) v = off[t - d];
        __syncthreads();
        if (t < PN) off[t] += v;
        __syncthreads();
    }
    if (t < PN) { int ex = off[t] - cnt[t]; off[t] = ex; cur[t] = ex; }
    __syncthreads();
    for (int i = t; i < n; i += 512) {
        int2 e = q[i];
        int ls = e.x & 31;
        int pos = atomicAdd(&cur[ls], 1);
        int2 pk;
        pk.x = (int)(((unsigned int)e.x) >> 5);   // dst (unsigned shift)
        pk.y = e.y;
        csr[pos] = pk;
    }
    __syncthreads();

    // ---- Phase B: 4-node-interleaved gather ----
    int wid  = t >> 6;
    int lane = t & 63;
    const unsigned int* xu = reinterpret_cast<const unsigned int*>(xh);

    int lsA = wid, lsB = wid + 8, lsC = wid + 16, lsD = wid + 24;
    int jA = off[lsA], eA = jA + cnt[lsA];
    int jB = off[lsB], eB = jB + cnt[lsB];
    int jC = off[lsC], eC = jC + cnt[lsC];
    int jD = off[lsD], eD = jD + cnt[lsD];

    float axA0=0,axA1=0,ayA0=0,ayA1=0,dgA0=0,dgA1=0;
    float axB0=0,axB1=0,ayB0=0,ayB1=0,dgB0=0,dgB1=0;
    float axC0=0,axC1=0,ayC0=0,ayC1=0,dgC0=0,dgC1=0;
    float axD0=0,axD1=0,ayD0=0,ayD1=0,dgD0=0,dgD1=0;

    // joint loop: up to 16 loads in flight across 4 independent chains
    while (true) {
        bool a4 = (jA + 3 < eA), b4 = (jB + 3 < eB);
        bool c4 = (jC + 3 < eC), d4 = (jD + 3 < eD);
        if (!(a4 | b4 | c4 | d4)) break;
        if (a4) { gath4(csr, xu, lane, jA, axA0, axA1, ayA0, ayA1, dgA0, dgA1); jA += 4; }
        if (b4) { gath4(csr, xu, lane, jB, axB0, axB1, ayB0, ayB1, dgB0, dgB1); jB += 4; }
        if (c4) { gath4(csr, xu, lane, jC, axC0, axC1, ayC0, ayC1, dgC0, dgC1); jC += 4; }
        if (d4) { gath4(csr, xu, lane, jD, axD0, axD1, ayD0, ayD1, dgD0, dgD1); jD += 4; }
    }
    // scalar tails (<=3 edges each)
    for (; jA < eA; ++jA) gath1(csr, xu, lane, jA, axA0, ayA0, dgA0);
    for (; jB < eB; ++jB) gath1(csr, xu, lane, jB, axB0, ayB0, dgB0);
    for (; jC < eC; ++jC) gath1(csr, xu, lane, jC, axC0, ayC0, dgC0);
    for (; jD < eD; ++jD) gath1(csr, xu, lane, jD, axD0, ayD0, dgD0);

    h1store(h1s, lsA, lane, axA0 + axA1, ayA0 + ayA1, dgA0 + dgA1);
    h1store(h1s, lsB, lane, axB0 + axB1, ayB0 + ayB1, dgB0 + dgB1);
    h1store(h1s, lsC, lane, axC0 + axC1, ayC0 + ayC1, dgC0 + dgC1);
    h1store(h1s, lsD, lane, axD0 + axD1, ayD0 + ayD1, dgD0 + dgD1);
    __syncthreads();

    // ---- Phase C: GEMM. Wave wid covers cols [wid*16, wid*16+16). ----
    int lr = lane & 15;
    int lk = lane >> 4;
    int r0 = b * PN;

    f32x4 acc[2];
    #pragma unroll
    for (int mf = 0; mf < 2; ++mf) acc[mf] = (f32x4){0.f, 0.f, 0.f, 0.f};

    #pragma unroll
    for (int ks = 0; ks < 8; ++ks) {
        bf16x8 a[2];
        if (ks < 4) {
            int coff = ks * 32 + lk * 8;
            #pragma unroll
            for (int mf = 0; mf < 2; ++mf) {
                int row = r0 + mf * 16 + lr;
                if (row >= N_NODES) row = N_NODES - 1;
                a[mf] = *reinterpret_cast<const bf16x8*>(
                    xh + (size_t)row * DIM + coff);
            }
        } else {
            int ucoff = (ks - 4) * 16 + lk * 4;
            #pragma unroll
            for (int mf = 0; mf < 2; ++mf) {
                int row = mf * 16 + lr;
                a[mf] = *reinterpret_cast<const bf16x8*>(
                    &h1s[row * 64 + (ucoff ^ ((row & 7) << 2))]);
            }
        }
        bf16x8 bq = *reinterpret_cast<const bf16x8*>(
            wfrag + ((size_t)((wid * 8 + ks) * 64 + lane)) * 8);
        #pragma unroll
        for (int mf = 0; mf < 2; ++mf)
            acc[mf] = __builtin_amdgcn_mfma_f32_16x16x32_bf16(
                a[mf], bq, acc[mf], 0, 0, 0);
    }

    #pragma unroll
    for (int mf = 0; mf < 2; ++mf) {
        int col = wid * 16 + lr;
        #pragma unroll
        for (int rr = 0; rr < 4; ++rr) {
            int row = r0 + mf * 16 + lk * 4 + rr;
            if (row < N_NODES)
                out[(size_t)row * DIM + col] = acc[mf][rr];
        }
    }
}

extern "C" void kernel_launch(void* const* d_in, const int* in_sizes, int n_in,
                              void* d_out, int out_size, void* d_ws, size_t ws_size,
                              hipStream_t stream) {
    const float* x    = (const float*)d_in[0];
    const float* W    = (const float*)d_in[1];
    const int*   esrc = (const int*)d_in[2];
    const int*   edst = (const int*)d_in[3];
    const float* eval = (const float*)d_in[4];
    float* out = (float*)d_out;

    // ws layout (~23.8 MB):
    //   xh     : N*DIM bf16            (12.8 MB)
    //   queue  : NPART*QCAP int2       ( 9.6 MB)
    //   counts : T_TILES*NPART ints    ( 1.2 MB)
    //   qcount : NPART ints            ( 6 KB)
    //   wfrag  : 32768 bf16            (64 KB)
    unsigned short* xh  = (unsigned short*)d_ws;
    int2* queue  = (int2*)(xh + (size_t)N_NODES * DIM);
    int*  counts = (int*)(queue + (size_t)NPART * QCAP);
    int*  qcount = counts + (size_t)T_TILES * NPART;
    unsigned short* wfrag = (unsigned short*)(qcount + NPART);

    bincount_kernel<<<T_TILES, 512, 0, stream>>>(esrc, counts);
    scan_xconv_wconv_kernel<<<NPART + XB + WCONV_B, 256, 0, stream>>>(
        counts, qcount, x, xh, W, wfrag);
    place_kernel<<<T_TILES, 512, 0, stream>>>(esrc, edst, eval, counts, queue);
    gather_gemm_kernel<<<NPART, 512, 0, stream>>>(xh, queue, qcount, wfrag, out);
}